// Round 10
// baseline (489.032 us; speedup 1.0000x reference)
//
#include <hip/hip_runtime.h>
#include <cmath>

// Problem constants (match reference setup_inputs)
#define NN 50000
#define EE 800000
#define ET (EE + NN)   // edges + self loops
#define IN_DIM 256
#define HID 72

typedef __attribute__((ext_vector_type(8))) short s8v;   // bf16 x8 MFMA frag
typedef __attribute__((ext_vector_type(4))) short s4v;
typedef __attribute__((ext_vector_type(4))) float f4v;   // MFMA acc

__device__ __forceinline__ ushort f2bf(float x) {
    uint u = __float_as_uint(x);
    return (ushort)((u + 0x7fffu + ((u >> 16) & 1u)) >> 16);   // RNE
}
__device__ __forceinline__ float bf2f(ushort h) {
    return __uint_as_float(((uint)h) << 16);
}
__device__ __forceinline__ void split4(const float4& v, s4v& h, s4v& l) {
    ushort h0 = f2bf(v.x), h1 = f2bf(v.y), h2 = f2bf(v.z), h3 = f2bf(v.w);
    h = (s4v){(short)h0, (short)h1, (short)h2, (short)h3};
    l = (s4v){(short)f2bf(v.x - bf2f(h0)), (short)f2bf(v.y - bf2f(h1)),
              (short)f2bf(v.z - bf2f(h2)), (short)f2bf(v.w - bf2f(h3))};
}
__device__ __forceinline__ f4v mfma16(s8v a, s8v b, f4v c) {
    return __builtin_amdgcn_mfma_f32_16x16x32_bf16(a, b, c, 0, 0, 0);
}

// ---------------------------------------------------------------------------
// CSR construction: histogram -> hierarchical scan -> scatter
// ---------------------------------------------------------------------------
__global__ void hist_kernel(const int* __restrict__ ei, int* __restrict__ deg) {
    int i = blockIdx.x * blockDim.x + threadIdx.x;
    if (i >= ET) return;
    int dst = (i < EE) ? ei[EE + i] : (i - EE);
    atomicAdd(&deg[dst], 1);
}

__global__ __launch_bounds__(256) void scan1_kernel(const int* __restrict__ deg,
        int* __restrict__ tmp, int* __restrict__ bsum, int n) {
    __shared__ int sh[256];
    int tid = threadIdx.x;
    int i = blockIdx.x * 256 + tid;
    sh[tid] = (i < n) ? deg[i] : 0;
    __syncthreads();
    for (int off = 1; off < 256; off <<= 1) {
        int t = (tid >= off) ? sh[tid - off] : 0;
        __syncthreads();
        sh[tid] += t;
        __syncthreads();
    }
    if (i < n) tmp[i] = sh[tid];
    if (tid == 255) bsum[blockIdx.x] = sh[255];
}

__global__ __launch_bounds__(256) void scan2_kernel(int* __restrict__ bsum, int nb) {
    __shared__ int sh[256];
    int tid = threadIdx.x;
    sh[tid] = (tid < nb) ? bsum[tid] : 0;
    __syncthreads();
    for (int off = 1; off < 256; off <<= 1) {
        int t = (tid >= off) ? sh[tid - off] : 0;
        __syncthreads();
        sh[tid] += t;
        __syncthreads();
    }
    if (tid < nb) bsum[tid] = sh[tid];
}

__global__ __launch_bounds__(256) void scan3_kernel(const int* __restrict__ tmp,
        const int* __restrict__ bsum, int* __restrict__ rowptr, int n) {
    int i = blockIdx.x * 256 + threadIdx.x;
    if (i == 0) rowptr[0] = 0;
    if (i < n) {
        int off = (blockIdx.x > 0) ? bsum[blockIdx.x - 1] : 0;
        rowptr[i + 1] = tmp[i] + off;
    }
}

__global__ void scatter_kernel(const int* __restrict__ ei, const int* __restrict__ rowptr,
                               int* __restrict__ cursor, int* __restrict__ csr) {
    int i = blockIdx.x * blockDim.x + threadIdx.x;
    if (i >= ET) return;
    int src = (i < EE) ? ei[i] : (i - EE);
    int dst = (i < EE) ? ei[EE + i] : (i - EE);
    int pos = atomicAdd(&cursor[dst], 1);
    csr[rowptr[dst] + pos] = src;
}

// ---------------------------------------------------------------------------
// Fused prep: split+transpose all 4 weights to (hi,lo) bf16 Bt[h][n][k],
// plus layer-1 projected attention vectors.  One dispatch.
// ---------------------------------------------------------------------------
__device__ __forceinline__ void wsplit_one(const float* W, int ldw, int K,
        int idx, short* outH, short* outL) {
    int h = idx / (72 * K);
    int rem = idx - h * 72 * K;
    int n = rem / K, k = rem - n * K;
    float v = W[(size_t)k * ldw + h * 72 + n];
    ushort hi = f2bf(v);
    outH[idx] = (short)hi;
    outL[idx] = (short)f2bf(v - bf2f(hi));
}

#define PR0 18432            // W_in  (K=256, NH=1, ldw=72)
#define PR1 (PR0 + 20736)    // W1    (K=72,  NH=4, ldw=288)
#define PR2 (PR1 + 20736)    // W2    (K=288, NH=1, ldw=72)
#define PR3 (PR2 + 5184)     // W3    (K=72,  NH=1, ldw=72)
#define PRTOT (PR3 + 288)    // attnproj (288)

__global__ __launch_bounds__(256) void prep_kernel(
        const float* __restrict__ W_in, const float* __restrict__ W1,
        const float* __restrict__ W2, const float* __restrict__ W3,
        const float* __restrict__ a_src, const float* __restrict__ a_dst,
        short* __restrict__ BtInH, short* __restrict__ BtInL,
        short* __restrict__ Bt1H, short* __restrict__ Bt1L,
        short* __restrict__ Bt2H, short* __restrict__ Bt2L,
        short* __restrict__ Bt3H, short* __restrict__ Bt3L,
        float* __restrict__ wsrc, float* __restrict__ wdst) {
    int gid = blockIdx.x * 256 + threadIdx.x;
    if (gid < PR0) {
        wsplit_one(W_in, 72, 256, gid, BtInH, BtInL);
    } else if (gid < PR1) {
        wsplit_one(W1, 288, 72, gid - PR0, Bt1H, Bt1L);
    } else if (gid < PR2) {
        wsplit_one(W2, 72, 288, gid - PR1, Bt2H, Bt2L);
    } else if (gid < PR3) {
        wsplit_one(W3, 72, 72, gid - PR2, Bt3H, Bt3L);
    } else if (gid < PRTOT) {
        int j = gid - PR3;                 // j = h*72 + k
        int h = j / HID, k = j % HID;
        const float* wrow = W1 + (size_t)k * (4 * HID) + h * HID;
        const float* as = a_src + h * HID;
        const float* ad = a_dst + h * HID;
        float s = 0.f, d = 0.f;
        for (int c = 0; c < HID; ++c) {
            float w = wrow[c];
            s = fmaf(w, as[c], s);
            d = fmaf(w, ad[c], d);
        }
        wsrc[j] = s;
        wdst[j] = d;
    }
}

// ---------------------------------------------------------------------------
// Split-bf16 MFMA GEMM, register-prefetch + ping-pong LDS (1 barrier/tile).
// C[M,72] = A[M,K] @ B[K,72] (+bias)(+ELU)(+logits).  A fp32 (split to
// hi/lo bf16 in staging); B pre-split/transposed bf16 (Bt[n][k]).
// Tile 64 rows x 72 cols (pad 80); 4 waves x 16-row strip x 5 n-frags;
// 3 MFMAs per frag pair (hi*hi + hi*lo + lo*hi; lo*lo ~2^-18 dropped).
// Barrier argument: a wave's LDS reads of buffer b (tile t) complete
// before it passes sync(t+1) (syncthreads drains lgkmcnt); buffer b is
// next overwritten at commit(t+2), which is after sync(t+1).  Safe.
// ---------------------------------------------------------------------------
template <int NLOGIT, bool ELU_EPI, bool BATCHED>
__global__ __launch_bounds__(256) void gemm_mfma(
        const float* __restrict__ A, const short* __restrict__ BtH,
        const short* __restrict__ BtL, const float* __restrict__ bias,
        float* __restrict__ C,
        const float* __restrict__ lvs, const float* __restrict__ lvd,
        float* __restrict__ ls, float* __restrict__ ld,
        int M, int K, int lda, int Nfull) {
    __shared__ __align__(16) short AhS[2][64 * 40], AlS[2][64 * 40];
    __shared__ __align__(16) short BhS[2][80 * 40], BlS[2][80 * 40];

    int tid = threadIdx.x;
    int row0 = blockIdx.x * 64;
    int hh = BATCHED ? blockIdx.y : 0;
    int aoff = BATCHED ? hh * 72 : 0;
    int coff = BATCHED ? hh * 72 : 0;
    const short* bhg = BtH + (size_t)hh * 72 * K;
    const short* blg = BtL + (size_t)hh * 72 * K;

    // zero n-pad rows 72..79 in both buffers (never rewritten)
    for (int i = tid; i < 8 * 40; i += 256) {
        BhS[0][72 * 40 + i] = 0; BlS[0][72 * 40 + i] = 0;
        BhS[1][72 * 40 + i] = 0; BlS[1][72 * 40 + i] = 0;
    }

    int w = tid >> 6;
    int lane = tid & 63;
    int q = lane >> 4, l16 = lane & 15;

    f4v acc[5];
    #pragma unroll
    for (int f = 0; f < 5; ++f) acc[f] = (f4v)0.f;

    int ar = tid >> 2;
    int aseg = tid & 3;
    bool arok = (row0 + ar) < M;
    const float* aptr = A + (size_t)(row0 + ar) * lda + aoff;
    int bn0 = tid >> 2, bq0 = tid & 3;
    int bn1 = (tid + 256) >> 2;

    float4 va, vb;
    s8v bh0, bl0, bh1, bl1;
    auto gload = [&](int k0) {
        va = (float4){0, 0, 0, 0};
        vb = (float4){0, 0, 0, 0};
        int ka = k0 + aseg * 8;
        if (arok && ka < K)     va = *(const float4*)(aptr + ka);
        if (arok && ka + 4 < K) vb = *(const float4*)(aptr + ka + 4);
        bh0 = (s8v)0; bl0 = (s8v)0;
        int kb = k0 + bq0 * 8;
        if (kb < K) {
            bh0 = *(const s8v*)(bhg + (size_t)bn0 * K + kb);
            bl0 = *(const s8v*)(blg + (size_t)bn0 * K + kb);
        }
        bh1 = (s8v)0; bl1 = (s8v)0;
        if (tid < 32 && kb < K) {
            bh1 = *(const s8v*)(bhg + (size_t)bn1 * K + kb);
            bl1 = *(const s8v*)(blg + (size_t)bn1 * K + kb);
        }
    };
    auto commit = [&](int buf) {
        s4v h0, l0, h1, l1;
        split4(va, h0, l0);
        split4(vb, h1, l1);
        *(s4v*)&AhS[buf][ar * 40 + aseg * 8]     = h0;
        *(s4v*)&AhS[buf][ar * 40 + aseg * 8 + 4] = h1;
        *(s4v*)&AlS[buf][ar * 40 + aseg * 8]     = l0;
        *(s4v*)&AlS[buf][ar * 40 + aseg * 8 + 4] = l1;
        *(s8v*)&BhS[buf][bn0 * 40 + bq0 * 8] = bh0;
        *(s8v*)&BlS[buf][bn0 * 40 + bq0 * 8] = bl0;
        if (tid < 32) {
            *(s8v*)&BhS[buf][bn1 * 40 + bq0 * 8] = bh1;
            *(s8v*)&BlS[buf][bn1 * 40 + bq0 * 8] = bl1;
        }
    };

    int ntiles = (K + 31) / 32;
    gload(0);
    for (int t = 0; t < ntiles; ++t) {
        int buf = t & 1;
        commit(buf);
        __syncthreads();
        if (t + 1 < ntiles) gload((t + 1) * 32);
        s8v ah = *(const s8v*)&AhS[buf][(w * 16 + l16) * 40 + q * 8];
        s8v al = *(const s8v*)&AlS[buf][(w * 16 + l16) * 40 + q * 8];
        #pragma unroll
        for (int f = 0; f < 5; ++f) {
            s8v bh = *(const s8v*)&BhS[buf][(f * 16 + l16) * 40 + q * 8];
            s8v bl = *(const s8v*)&BlS[buf][(f * 16 + l16) * 40 + q * 8];
            acc[f] = mfma16(ah, bh, acc[f]);
            acc[f] = mfma16(ah, bl, acc[f]);
            acc[f] = mfma16(al, bh, acc[f]);
        }
    }

    float v[5][4];
    #pragma unroll
    for (int f = 0; f < 5; ++f) {
        int col = f * 16 + l16;
        bool cv = col < 72;
        #pragma unroll
        for (int r = 0; r < 4; ++r) {
            float t = acc[f][r];
            if (cv && bias) t += bias[coff + col];
            if (ELU_EPI) t = (t > 0.f) ? t : expm1f(t);
            v[f][r] = cv ? t : 0.f;
        }
    }
    if (NLOGIT > 0) {
        #pragma unroll
        for (int h2 = 0; h2 < NLOGIT; ++h2) {
            #pragma unroll
            for (int r = 0; r < 4; ++r) {
                float s = 0.f, d = 0.f;
                #pragma unroll
                for (int f = 0; f < 5; ++f) {
                    int col = f * 16 + l16;
                    float lw = (col < 72) ? lvs[h2 * 72 + col] : 0.f;
                    float dw = (col < 72) ? lvd[h2 * 72 + col] : 0.f;
                    s = fmaf(v[f][r], lw, s);
                    d = fmaf(v[f][r], dw, d);
                }
                s += __shfl_xor(s, 1); s += __shfl_xor(s, 2);
                s += __shfl_xor(s, 4); s += __shfl_xor(s, 8);
                d += __shfl_xor(d, 1); d += __shfl_xor(d, 2);
                d += __shfl_xor(d, 4); d += __shfl_xor(d, 8);
                int gr = row0 + w * 16 + q * 4 + r;
                if (l16 == 0 && gr < M) {
                    ls[gr * NLOGIT + h2] = s;
                    ld[gr * NLOGIT + h2] = d;
                }
            }
        }
    }
    #pragma unroll
    for (int f = 0; f < 5; ++f) {
        int col = f * 16 + l16;
        if (col >= 72) continue;
        #pragma unroll
        for (int r = 0; r < 4; ++r) {
            int gr = row0 + w * 16 + q * 4 + r;
            if (gr < M) C[(size_t)gr * Nfull + coff + col] = v[f][r];
        }
    }
}

// ---------------------------------------------------------------------------
// Softmax-weighted gather of 72-wide feature rows; one wave per dst node.
// deg<=64 fast path: merged softmax sweep; gather 8-edge unrolled with
// padded edge count (zero-weight clamped edges) — 16 loads in flight.
// ---------------------------------------------------------------------------
template <int H, bool EPI, bool ADD_RES>
__global__ __launch_bounds__(64) void agg_gather(
        const float* __restrict__ feat, const float* __restrict__ ls, const float* __restrict__ ld,
        const int* __restrict__ rowptr, const int* __restrict__ csr,
        const float* __restrict__ bias, const float* __restrict__ res,
        float* __restrict__ out, int n) {
    __shared__ float wsh[64 * H];
    __shared__ int ssh[64];
    int wid = blockIdx.x;
    int lane = threadIdx.x;
    int rp0 = rowptr[wid], rp1 = rowptr[wid + 1];
    int deg = rp1 - rp0;

    float ldh[H];
    if (H == 4) {
        float4 t = ((const float4*)ld)[wid];
        ldh[0] = t.x; ldh[1] = t.y; ldh[2] = t.z; ldh[3] = t.w;
    } else {
        ldh[0] = ld[wid];
    }

    float acc[H][2];
    #pragma unroll
    for (int h = 0; h < H; ++h) { acc[h][0] = 0.f; acc[h][1] = 0.f; }

    if (deg <= 64) {
        // ---- merged softmax sweep: one edge per lane (clamped for pad) ----
        bool act = lane < deg;
        int s = csr[rp0 + (act ? lane : 0)];   // valid index for all lanes
        ssh[lane] = s;
        float e[H];
        float ev[H];
        if (H == 4) {
            float4 lv = ((const float4*)ls)[s];
            ev[0] = lv.x; ev[1] = lv.y; ev[2] = lv.z; ev[3] = lv.w;
        } else {
            ev[0] = ls[s];
        }
        #pragma unroll
        for (int h = 0; h < H; ++h) {
            float vv = ev[h] + ldh[h];
            vv = (vv > 0.f) ? vv : 0.2f * vv;
            e[h] = act ? vv : -__builtin_inff();
        }
        float wv[H];
        #pragma unroll
        for (int h = 0; h < H; ++h) {
            float mh = e[h];
            #pragma unroll
            for (int off = 32; off; off >>= 1) mh = fmaxf(mh, __shfl_xor(mh, off));
            float ph = act ? expf(e[h] - mh) : 0.f;
            float sh = ph;
            #pragma unroll
            for (int off = 32; off; off >>= 1) sh += __shfl_xor(sh, off);
            wv[h] = ph / fmaxf(sh, 1e-16f);   // 0 for pad lanes
        }
        if (H == 4) {
            ((float4*)wsh)[lane] = (float4){wv[0], wv[1], wv[2], wv[3]};
        } else {
            wsh[lane] = wv[0];
        }
        __syncthreads();
        // ---- weighted gather, 8-edge unroll, padded to x8 ----
        const float* fl = feat + lane;
        const float* fl2 = feat + 64 + lane;
        bool tail = lane < 8;
        int nb = (deg + 7) & ~7;
        for (int t = 0; t < nb; t += 8) {
            int si[8];
            #pragma unroll
            for (int u = 0; u < 8; ++u) si[u] = ssh[t + u];
            float a[8], b[8];
            #pragma unroll
            for (int u = 0; u < 8; ++u) a[u] = fl[(size_t)si[u] * HID];
            #pragma unroll
            for (int u = 0; u < 8; ++u) b[u] = tail ? fl2[(size_t)si[u] * HID] : 0.f;
            if (H == 4) {
                #pragma unroll
                for (int u = 0; u < 8; ++u) {
                    float4 we = ((const float4*)wsh)[t + u];   // b128 broadcast
                    float wgt[4] = {we.x, we.y, we.z, we.w};
                    #pragma unroll
                    for (int h = 0; h < 4; ++h) {
                        acc[h][0] = fmaf(wgt[h], a[u], acc[h][0]);
                        acc[h][1] = fmaf(wgt[h], b[u], acc[h][1]);
                    }
                }
            } else {
                #pragma unroll
                for (int u = 0; u < 8; ++u) {
                    float wgt = wsh[t + u];
                    acc[0][0] = fmaf(wgt, a[u], acc[0][0]);
                    acc[0][1] = fmaf(wgt, b[u], acc[0][1]);
                }
            }
        }
    } else {
        // ---- generic 3-pass fallback (rare) ----
        float m[H];
        #pragma unroll
        for (int h = 0; h < H; ++h) m[h] = -__builtin_inff();
        for (int i = rp0 + lane; i < rp1; i += 64) {
            int s = csr[i];
            float e[H];
            if (H == 4) {
                float4 lv = ((const float4*)ls)[s];
                e[0] = lv.x; e[1] = lv.y; e[2] = lv.z; e[3] = lv.w;
            } else {
                e[0] = ls[s];
            }
            #pragma unroll
            for (int h = 0; h < H; ++h) {
                float vv = e[h] + ldh[h];
                vv = (vv > 0.f) ? vv : 0.2f * vv;
                m[h] = fmaxf(m[h], vv);
            }
        }
        #pragma unroll
        for (int h = 0; h < H; ++h)
            #pragma unroll
            for (int off = 32; off; off >>= 1) m[h] = fmaxf(m[h], __shfl_xor(m[h], off));

        float ssum[H];
        #pragma unroll
        for (int h = 0; h < H; ++h) ssum[h] = 0.f;
        for (int i = rp0 + lane; i < rp1; i += 64) {
            int s = csr[i];
            float e[H];
            if (H == 4) {
                float4 lv = ((const float4*)ls)[s];
                e[0] = lv.x; e[1] = lv.y; e[2] = lv.z; e[3] = lv.w;
            } else {
                e[0] = ls[s];
            }
            #pragma unroll
            for (int h = 0; h < H; ++h) {
                float vv = e[h] + ldh[h];
                vv = (vv > 0.f) ? vv : 0.2f * vv;
                ssum[h] += expf(vv - m[h]);
            }
        }
        #pragma unroll
        for (int h = 0; h < H; ++h)
            #pragma unroll
            for (int off = 32; off; off >>= 1) ssum[h] += __shfl_xor(ssum[h], off);
        float inv[H];
        #pragma unroll
        for (int h = 0; h < H; ++h) inv[h] = 1.f / fmaxf(ssum[h], 1e-16f);

        for (int base = rp0; base < rp1; base += 64) {
            int i = base + lane;
            int lim = min(64, rp1 - base);
            if (i < rp1) {
                int s = csr[i];
                ssh[lane] = s;
                float e[H];
                if (H == 4) {
                    float4 lv = ((const float4*)ls)[s];
                    e[0] = lv.x; e[1] = lv.y; e[2] = lv.z; e[3] = lv.w;
                } else {
                    e[0] = ls[s];
                }
                #pragma unroll
                for (int h = 0; h < H; ++h) {
                    float vv = e[h] + ldh[h];
                    vv = (vv > 0.f) ? vv : 0.2f * vv;
                    wsh[lane * H + h] = expf(vv - m[h]) * inv[h];
                }
            }
            __syncthreads();
            int t = 0;
            for (; t + 2 <= lim; t += 2) {
                int s0 = ssh[t], s1 = ssh[t + 1];
                const float* r0 = feat + (size_t)s0 * HID;
                const float* r1 = feat + (size_t)s1 * HID;
                float a0 = r0[lane], a1 = r1[lane];
                float b0 = 0.f, b1 = 0.f;
                if (lane < 8) { b0 = r0[64 + lane]; b1 = r1[64 + lane]; }
                #pragma unroll
                for (int h = 0; h < H; ++h) {
                    float w0 = wsh[t * H + h], w1 = wsh[(t + 1) * H + h];
                    acc[h][0] += w0 * a0 + w1 * a1;
                    acc[h][1] += w0 * b0 + w1 * b1;
                }
            }
            if (t < lim) {
                int s0 = ssh[t];
                const float* r0 = feat + (size_t)s0 * HID;
                float a0 = r0[lane];
                float b0 = (lane < 8) ? r0[64 + lane] : 0.f;
                #pragma unroll
                for (int h = 0; h < H; ++h) {
                    float w0 = wsh[t * H + h];
                    acc[h][0] = fmaf(w0, a0, acc[h][0]);
                    acc[h][1] = fmaf(w0, b0, acc[h][1]);
                }
            }
            __syncthreads();
        }
    }

    // ---- common epilogue ----
    #pragma unroll
    for (int h = 0; h < H; ++h) {
        float v0 = acc[h][0], v1 = acc[h][1];
        if (EPI) {
            v0 += bias[lane];
            v0 = (v0 > 0.f) ? v0 : expm1f(v0);
            if (ADD_RES) v0 += res[(size_t)wid * HID + lane];
            if (lane < 8) {
                v1 += bias[64 + lane];
                v1 = (v1 > 0.f) ? v1 : expm1f(v1);
                if (ADD_RES) v1 += res[(size_t)wid * HID + 64 + lane];
            }
        }
        out[(size_t)wid * (H * HID) + h * HID + lane] = v0;
        if (lane < 8) out[(size_t)wid * (H * HID) + h * HID + 64 + lane] = v1;
    }
}

// ---------------------------------------------------------------------------
// Score MLP: out[n] = relu(h[n,:]@Ws1 + bs1) @ Ws2 + bs2.  32 lanes / node.
// ---------------------------------------------------------------------------
__global__ __launch_bounds__(256) void score_kernel(
        const float* __restrict__ h, const float* __restrict__ Ws1, const float* __restrict__ bs1,
        const float* __restrict__ Ws2, const float* __restrict__ bs2,
        float* __restrict__ out, int n) {
    int sub = threadIdx.x >> 5;
    int j = threadIdx.x & 31;
    int node = blockIdx.x * 8 + sub;
    if (node >= n) return;
    const float* row = h + (size_t)node * HID;
    float acc = bs1[j];
    #pragma unroll 8
    for (int c = 0; c < HID; ++c) acc = fmaf(row[c], Ws1[c * 32 + j], acc);
    float v = fmaxf(acc, 0.f) * Ws2[j];
    #pragma unroll
    for (int off = 16; off; off >>= 1) v += __shfl_down(v, off, 32);
    if (j == 0) out[node] = v + bs2[0];
}

// ---------------------------------------------------------------------------
extern "C" void kernel_launch(void* const* d_in, const int* in_sizes, int n_in,
                              void* d_out, int out_size, void* d_ws, size_t ws_size,
                              hipStream_t stream) {
    const float* x      = (const float*)d_in[0];
    const int*   ei     = (const int*)  d_in[1];
    const float* W_in   = (const float*)d_in[2];
    const float* b_in   = (const float*)d_in[3];
    const float* W1     = (const float*)d_in[4];
    const float* a_src1 = (const float*)d_in[5];
    const float* a_dst1 = (const float*)d_in[6];
    const float* b1     = (const float*)d_in[7];
    const float* W2     = (const float*)d_in[8];
    const float* a_src2 = (const float*)d_in[9];
    const float* a_dst2 = (const float*)d_in[10];
    const float* b2     = (const float*)d_in[11];
    const float* W3     = (const float*)d_in[12];
    const float* a_src3 = (const float*)d_in[13];
    const float* a_dst3 = (const float*)d_in[14];
    const float* b3     = (const float*)d_in[15];
    const float* Ws1    = (const float*)d_in[16];
    const float* bs1    = (const float*)d_in[17];
    const float* Ws2    = (const float*)d_in[18];
    const float* bs2    = (const float*)d_in[19];
    float* out = (float*)d_out;

    // workspace carve-up (deg+cursor adjacent -> one memset)
    float* ws    = (float*)d_ws;
    float* x0    = ws;                        // N*72
    float* bufA  = x0 + (size_t)NN * HID;     // N*288 (agg1 / hp2 / hp3)
    float* bufB  = bufA + (size_t)NN * 288;   // N*288 (h1 / h2 / h3)
    float* ls    = bufB + (size_t)NN * 288;   // N*4
    float* ld    = ls + (size_t)NN * 4;       // N*4
    float* wsrc1 = ld + (size_t)NN * 4;       // 288
    float* wdst1 = wsrc1 + 288;               // 288
    int* deg    = (int*)(wdst1 + 288);        // N
    int* cursor = deg + NN;                   // N (adjacent to deg)
    int* rowptr = cursor + NN;                // N+1
    int* tmp    = rowptr + NN + 1;            // N
    int* bsum   = tmp + NN;                   // 256
    int* csr    = bsum + 256;                 // ET
    uintptr_t bp = ((uintptr_t)(csr + ET) + 15) & ~(uintptr_t)15;
    short* BtInH = (short*)bp;                // 72*256
    short* BtInL = BtInH + 18432;
    short* Bt1H  = BtInL + 18432;             // 4*72*72
    short* Bt1L  = Bt1H + 20736;
    short* Bt2H  = Bt1L + 20736;              // 72*288
    short* Bt2L  = Bt2H + 20736;
    short* Bt3H  = Bt2L + 20736;              // 72*72
    short* Bt3L  = Bt3H + 5184;

    hipMemsetAsync(deg, 0, 2 * NN * sizeof(int), stream);   // deg + cursor

    const int egrid = (ET + 255) / 256;
    const int sgrid = (NN + 255) / 256;
    hist_kernel<<<egrid, 256, 0, stream>>>(ei, deg);
    scan1_kernel<<<sgrid, 256, 0, stream>>>(deg, tmp, bsum, NN);
    scan2_kernel<<<1, 256, 0, stream>>>(bsum, sgrid);
    scan3_kernel<<<sgrid, 256, 0, stream>>>(tmp, bsum, rowptr, NN);
    scatter_kernel<<<egrid, 256, 0, stream>>>(ei, rowptr, cursor, csr);

    prep_kernel<<<(PRTOT + 255) / 256, 256, 0, stream>>>(
        W_in, W1, W2, W3, a_src1, a_dst1,
        BtInH, BtInL, Bt1H, Bt1L, Bt2H, Bt2L, Bt3H, Bt3L, wsrc1, wdst1);

    const int mblocks = (NN + 63) / 64;   // 782
    // x0 = x @ W_in + b_in, fused layer-1 logits (4 heads via projections)
    gemm_mfma<4, false, false><<<dim3(mblocks, 1), 256, 0, stream>>>(
        x, BtInH, BtInL, b_in, x0, wsrc1, wdst1, ls, ld, NN, IN_DIM, IN_DIM, HID);
    // ---- layer 1 (aggregate in input space, then per-head GEMM + ELU) ----
    agg_gather<4, false, false><<<NN, 64, 0, stream>>>(
        x0, ls, ld, rowptr, csr, nullptr, nullptr, bufA, NN);
    gemm_mfma<0, true, true><<<dim3(mblocks, 4), 256, 0, stream>>>(
        bufA, Bt1H, Bt1L, b1, bufB, nullptr, nullptr, nullptr, nullptr, NN, HID, 288, 288);
    // ---- layer 2 ----
    gemm_mfma<1, false, false><<<dim3(mblocks, 1), 256, 0, stream>>>(
        bufB, Bt2H, Bt2L, nullptr, bufA, a_src2, a_dst2, ls, ld, NN, 288, 288, HID);
    agg_gather<1, true, false><<<NN, 64, 0, stream>>>(
        bufA, ls, ld, rowptr, csr, b2, nullptr, bufB, NN);
    // ---- layer 3 ----
    gemm_mfma<1, false, false><<<dim3(mblocks, 1), 256, 0, stream>>>(
        bufB, Bt3H, Bt3L, nullptr, bufA, a_src3, a_dst3, ls, ld, NN, HID, HID, HID);
    agg_gather<1, true, true><<<NN, 64, 0, stream>>>(
        bufA, ls, ld, rowptr, csr, b3, x0, bufB, NN);
    // ---- score head ----
    score_kernel<<<(NN + 7) / 8, 256, 0, stream>>>(bufB, Ws1, bs1, Ws2, bs2, out, NN);
}

// Round 11
// 474.323 us; speedup vs baseline: 1.0310x; 1.0310x over previous
//
#include <hip/hip_runtime.h>
#include <cmath>

// Problem constants (match reference setup_inputs)
#define NN 50000
#define EE 800000
#define ET (EE + NN)   // edges + self loops
#define IN_DIM 256
#define HID 72

typedef __attribute__((ext_vector_type(8))) short s8v;   // bf16 x8 MFMA frag
typedef __attribute__((ext_vector_type(4))) short s4v;
typedef __attribute__((ext_vector_type(4))) float f4v;   // MFMA acc

__device__ __forceinline__ ushort f2bf(float x) {
    uint u = __float_as_uint(x);
    return (ushort)((u + 0x7fffu + ((u >> 16) & 1u)) >> 16);   // RNE
}
__device__ __forceinline__ float bf2f(ushort h) {
    return __uint_as_float(((uint)h) << 16);
}
__device__ __forceinline__ void split4(const float4& v, s4v& h, s4v& l) {
    ushort h0 = f2bf(v.x), h1 = f2bf(v.y), h2 = f2bf(v.z), h3 = f2bf(v.w);
    h = (s4v){(short)h0, (short)h1, (short)h2, (short)h3};
    l = (s4v){(short)f2bf(v.x - bf2f(h0)), (short)f2bf(v.y - bf2f(h1)),
              (short)f2bf(v.z - bf2f(h2)), (short)f2bf(v.w - bf2f(h3))};
}
__device__ __forceinline__ f4v mfma16(s8v a, s8v b, f4v c) {
    return __builtin_amdgcn_mfma_f32_16x16x32_bf16(a, b, c, 0, 0, 0);
}

// ---------------------------------------------------------------------------
// CSR construction: histogram -> hierarchical scan -> scatter
// ---------------------------------------------------------------------------
__global__ void hist_kernel(const int* __restrict__ ei, int* __restrict__ deg) {
    int i = blockIdx.x * blockDim.x + threadIdx.x;
    if (i >= ET) return;
    int dst = (i < EE) ? ei[EE + i] : (i - EE);
    atomicAdd(&deg[dst], 1);
}

__global__ __launch_bounds__(256) void scan1_kernel(const int* __restrict__ deg,
        int* __restrict__ tmp, int* __restrict__ bsum, int n) {
    __shared__ int sh[256];
    int tid = threadIdx.x;
    int i = blockIdx.x * 256 + tid;
    sh[tid] = (i < n) ? deg[i] : 0;
    __syncthreads();
    for (int off = 1; off < 256; off <<= 1) {
        int t = (tid >= off) ? sh[tid - off] : 0;
        __syncthreads();
        sh[tid] += t;
        __syncthreads();
    }
    if (i < n) tmp[i] = sh[tid];
    if (tid == 255) bsum[blockIdx.x] = sh[255];
}

__global__ __launch_bounds__(256) void scan2_kernel(int* __restrict__ bsum, int nb) {
    __shared__ int sh[256];
    int tid = threadIdx.x;
    sh[tid] = (tid < nb) ? bsum[tid] : 0;
    __syncthreads();
    for (int off = 1; off < 256; off <<= 1) {
        int t = (tid >= off) ? sh[tid - off] : 0;
        __syncthreads();
        sh[tid] += t;
        __syncthreads();
    }
    if (tid < nb) bsum[tid] = sh[tid];
}

__global__ __launch_bounds__(256) void scan3_kernel(const int* __restrict__ tmp,
        const int* __restrict__ bsum, int* __restrict__ rowptr, int n) {
    int i = blockIdx.x * 256 + threadIdx.x;
    if (i == 0) rowptr[0] = 0;
    if (i < n) {
        int off = (blockIdx.x > 0) ? bsum[blockIdx.x - 1] : 0;
        rowptr[i + 1] = tmp[i] + off;
    }
}

__global__ void scatter_kernel(const int* __restrict__ ei, const int* __restrict__ rowptr,
                               int* __restrict__ cursor, int* __restrict__ csr) {
    int i = blockIdx.x * blockDim.x + threadIdx.x;
    if (i >= ET) return;
    int src = (i < EE) ? ei[i] : (i - EE);
    int dst = (i < EE) ? ei[EE + i] : (i - EE);
    int pos = atomicAdd(&cursor[dst], 1);
    csr[rowptr[dst] + pos] = src;
}

// ---------------------------------------------------------------------------
// Fused prep: split+transpose all 4 weights to (hi,lo) bf16 Bt[h][n][k],
// plus layer-1 projected attention vectors.  One dispatch.
// ---------------------------------------------------------------------------
__device__ __forceinline__ void wsplit_one(const float* W, int ldw, int K,
        int idx, short* outH, short* outL) {
    int h = idx / (72 * K);
    int rem = idx - h * 72 * K;
    int n = rem / K, k = rem - n * K;
    float v = W[(size_t)k * ldw + h * 72 + n];
    ushort hi = f2bf(v);
    outH[idx] = (short)hi;
    outL[idx] = (short)f2bf(v - bf2f(hi));
}

#define PR0 18432            // W_in  (K=256, NH=1, ldw=72)
#define PR1 (PR0 + 20736)    // W1    (K=72,  NH=4, ldw=288)
#define PR2 (PR1 + 20736)    // W2    (K=288, NH=1, ldw=72)
#define PR3 (PR2 + 5184)     // W3    (K=72,  NH=1, ldw=72)
#define PRTOT (PR3 + 288)    // attnproj (288)

__global__ __launch_bounds__(256) void prep_kernel(
        const float* __restrict__ W_in, const float* __restrict__ W1,
        const float* __restrict__ W2, const float* __restrict__ W3,
        const float* __restrict__ a_src, const float* __restrict__ a_dst,
        short* __restrict__ BtInH, short* __restrict__ BtInL,
        short* __restrict__ Bt1H, short* __restrict__ Bt1L,
        short* __restrict__ Bt2H, short* __restrict__ Bt2L,
        short* __restrict__ Bt3H, short* __restrict__ Bt3L,
        float* __restrict__ wsrc, float* __restrict__ wdst) {
    int gid = blockIdx.x * 256 + threadIdx.x;
    if (gid < PR0) {
        wsplit_one(W_in, 72, 256, gid, BtInH, BtInL);
    } else if (gid < PR1) {
        wsplit_one(W1, 288, 72, gid - PR0, Bt1H, Bt1L);
    } else if (gid < PR2) {
        wsplit_one(W2, 72, 288, gid - PR1, Bt2H, Bt2L);
    } else if (gid < PR3) {
        wsplit_one(W3, 72, 72, gid - PR2, Bt3H, Bt3L);
    } else if (gid < PRTOT) {
        int j = gid - PR3;                 // j = h*72 + k
        int h = j / HID, k = j % HID;
        const float* wrow = W1 + (size_t)k * (4 * HID) + h * HID;
        const float* as = a_src + h * HID;
        const float* ad = a_dst + h * HID;
        float s = 0.f, d = 0.f;
        for (int c = 0; c < HID; ++c) {
            float w = wrow[c];
            s = fmaf(w, as[c], s);
            d = fmaf(w, ad[c], d);
        }
        wsrc[j] = s;
        wdst[j] = d;
    }
}

// ---------------------------------------------------------------------------
// Split-bf16 MFMA GEMM with register-prefetch double buffering.
// Single LDS buffer (23 KB), two barriers per tile — measured faster than
// ping-pong dbuf (round 10: 2x LDS cost occupancy 27% vs 35%, +3M bank
// conflicts, gemm 62 vs ~50 us).  Blocks/CU beats barriers/block here.
// C[M,72] = A[M,K] @ B[K,72] (+bias)(+ELU)(+logits).  A fp32 (split to
// hi/lo bf16 in staging); B pre-split/transposed bf16 (Bt[n][k]).
// Tile 64 rows x 72 cols (pad 80); 4 waves x 16-row strip x 5 n-frags;
// 3 MFMAs per frag pair (hi*hi + hi*lo + lo*hi; lo*lo ~2^-18 dropped).
// ---------------------------------------------------------------------------
template <int NLOGIT, bool ELU_EPI, bool BATCHED>
__global__ __launch_bounds__(256) void gemm_mfma(
        const float* __restrict__ A, const short* __restrict__ BtH,
        const short* __restrict__ BtL, const float* __restrict__ bias,
        float* __restrict__ C,
        const float* __restrict__ lvs, const float* __restrict__ lvd,
        float* __restrict__ ls, float* __restrict__ ld,
        int M, int K, int lda, int Nfull) {
    __shared__ __align__(16) short AhS[64 * 40], AlS[64 * 40];   // [m][k] pad 40
    __shared__ __align__(16) short BhS[80 * 40], BlS[80 * 40];   // [n][k] pad 40

    int tid = threadIdx.x;
    int row0 = blockIdx.x * 64;
    int hh = BATCHED ? blockIdx.y : 0;
    int aoff = BATCHED ? hh * 72 : 0;
    int coff = BATCHED ? hh * 72 : 0;
    const short* bhg = BtH + (size_t)hh * 72 * K;
    const short* blg = BtL + (size_t)hh * 72 * K;

    for (int i = tid; i < 8 * 40; i += 256) {
        BhS[72 * 40 + i] = 0;
        BlS[72 * 40 + i] = 0;
    }

    int w = tid >> 6;
    int lane = tid & 63;
    int q = lane >> 4, l16 = lane & 15;

    f4v acc[5];
    #pragma unroll
    for (int f = 0; f < 5; ++f) acc[f] = (f4v)0.f;

    int ar = tid >> 2;
    int aseg = tid & 3;
    bool arok = (row0 + ar) < M;
    const float* aptr = A + (size_t)(row0 + ar) * lda + aoff;
    int bn0 = tid >> 2, bq0 = tid & 3;
    int bn1 = (tid + 256) >> 2;

    float4 va, vb;
    s8v bh0, bl0, bh1, bl1;
    auto gload = [&](int k0) {
        va = (float4){0, 0, 0, 0};
        vb = (float4){0, 0, 0, 0};
        int ka = k0 + aseg * 8;
        if (arok && ka < K)     va = *(const float4*)(aptr + ka);
        if (arok && ka + 4 < K) vb = *(const float4*)(aptr + ka + 4);
        bh0 = (s8v)0; bl0 = (s8v)0;
        int kb = k0 + bq0 * 8;
        if (kb < K) {
            bh0 = *(const s8v*)(bhg + (size_t)bn0 * K + kb);
            bl0 = *(const s8v*)(blg + (size_t)bn0 * K + kb);
        }
        bh1 = (s8v)0; bl1 = (s8v)0;
        if (tid < 32 && kb < K) {
            bh1 = *(const s8v*)(bhg + (size_t)bn1 * K + kb);
            bl1 = *(const s8v*)(blg + (size_t)bn1 * K + kb);
        }
    };
    auto commit = [&]() {
        s4v h0, l0, h1, l1;
        split4(va, h0, l0);
        split4(vb, h1, l1);
        *(s4v*)&AhS[ar * 40 + aseg * 8]     = h0;
        *(s4v*)&AhS[ar * 40 + aseg * 8 + 4] = h1;
        *(s4v*)&AlS[ar * 40 + aseg * 8]     = l0;
        *(s4v*)&AlS[ar * 40 + aseg * 8 + 4] = l1;
        *(s8v*)&BhS[bn0 * 40 + bq0 * 8] = bh0;
        *(s8v*)&BlS[bn0 * 40 + bq0 * 8] = bl0;
        if (tid < 32) {
            *(s8v*)&BhS[bn1 * 40 + bq0 * 8] = bh1;
            *(s8v*)&BlS[bn1 * 40 + bq0 * 8] = bl1;
        }
    };

    int ntiles = (K + 31) / 32;
    gload(0);
    for (int t = 0; t < ntiles; ++t) {
        commit();
        __syncthreads();
        if (t + 1 < ntiles) gload((t + 1) * 32);
        s8v ah = *(const s8v*)&AhS[(w * 16 + l16) * 40 + q * 8];
        s8v al = *(const s8v*)&AlS[(w * 16 + l16) * 40 + q * 8];
        #pragma unroll
        for (int f = 0; f < 5; ++f) {
            s8v bh = *(const s8v*)&BhS[(f * 16 + l16) * 40 + q * 8];
            s8v bl = *(const s8v*)&BlS[(f * 16 + l16) * 40 + q * 8];
            acc[f] = mfma16(ah, bh, acc[f]);
            acc[f] = mfma16(ah, bl, acc[f]);
            acc[f] = mfma16(al, bh, acc[f]);
        }
        __syncthreads();
    }

    float v[5][4];
    #pragma unroll
    for (int f = 0; f < 5; ++f) {
        int col = f * 16 + l16;
        bool cv = col < 72;
        #pragma unroll
        for (int r = 0; r < 4; ++r) {
            float t = acc[f][r];
            if (cv && bias) t += bias[coff + col];
            if (ELU_EPI) t = (t > 0.f) ? t : expm1f(t);
            v[f][r] = cv ? t : 0.f;
        }
    }
    if (NLOGIT > 0) {
        #pragma unroll
        for (int h2 = 0; h2 < NLOGIT; ++h2) {
            #pragma unroll
            for (int r = 0; r < 4; ++r) {
                float s = 0.f, d = 0.f;
                #pragma unroll
                for (int f = 0; f < 5; ++f) {
                    int col = f * 16 + l16;
                    float lw = (col < 72) ? lvs[h2 * 72 + col] : 0.f;
                    float dw = (col < 72) ? lvd[h2 * 72 + col] : 0.f;
                    s = fmaf(v[f][r], lw, s);
                    d = fmaf(v[f][r], dw, d);
                }
                s += __shfl_xor(s, 1); s += __shfl_xor(s, 2);
                s += __shfl_xor(s, 4); s += __shfl_xor(s, 8);
                d += __shfl_xor(d, 1); d += __shfl_xor(d, 2);
                d += __shfl_xor(d, 4); d += __shfl_xor(d, 8);
                int gr = row0 + w * 16 + q * 4 + r;
                if (l16 == 0 && gr < M) {
                    ls[gr * NLOGIT + h2] = s;
                    ld[gr * NLOGIT + h2] = d;
                }
            }
        }
    }
    #pragma unroll
    for (int f = 0; f < 5; ++f) {
        int col = f * 16 + l16;
        if (col >= 72) continue;
        #pragma unroll
        for (int r = 0; r < 4; ++r) {
            int gr = row0 + w * 16 + q * 4 + r;
            if (gr < M) C[(size_t)gr * Nfull + coff + col] = v[f][r];
        }
    }
}

// ---------------------------------------------------------------------------
// Softmax-weighted gather of 72-wide feature rows; one wave per dst node.
// deg<=64 fast path: merged softmax sweep; gather 8-edge unrolled with
// padded edge count (zero-weight clamped edges) — 16 loads in flight.
// ---------------------------------------------------------------------------
template <int H, bool EPI, bool ADD_RES>
__global__ __launch_bounds__(64) void agg_gather(
        const float* __restrict__ feat, const float* __restrict__ ls, const float* __restrict__ ld,
        const int* __restrict__ rowptr, const int* __restrict__ csr,
        const float* __restrict__ bias, const float* __restrict__ res,
        float* __restrict__ out, int n) {
    __shared__ float wsh[64 * H];
    __shared__ int ssh[64];
    int wid = blockIdx.x;
    int lane = threadIdx.x;
    int rp0 = rowptr[wid], rp1 = rowptr[wid + 1];
    int deg = rp1 - rp0;

    float ldh[H];
    if (H == 4) {
        float4 t = ((const float4*)ld)[wid];
        ldh[0] = t.x; ldh[1] = t.y; ldh[2] = t.z; ldh[3] = t.w;
    } else {
        ldh[0] = ld[wid];
    }

    float acc[H][2];
    #pragma unroll
    for (int h = 0; h < H; ++h) { acc[h][0] = 0.f; acc[h][1] = 0.f; }

    if (deg <= 64) {
        // ---- merged softmax sweep: one edge per lane (clamped for pad) ----
        bool act = lane < deg;
        int s = csr[rp0 + (act ? lane : 0)];   // valid index for all lanes
        ssh[lane] = s;
        float e[H];
        float ev[H];
        if (H == 4) {
            float4 lv = ((const float4*)ls)[s];
            ev[0] = lv.x; ev[1] = lv.y; ev[2] = lv.z; ev[3] = lv.w;
        } else {
            ev[0] = ls[s];
        }
        #pragma unroll
        for (int h = 0; h < H; ++h) {
            float vv = ev[h] + ldh[h];
            vv = (vv > 0.f) ? vv : 0.2f * vv;
            e[h] = act ? vv : -__builtin_inff();
        }
        float wv[H];
        #pragma unroll
        for (int h = 0; h < H; ++h) {
            float mh = e[h];
            #pragma unroll
            for (int off = 32; off; off >>= 1) mh = fmaxf(mh, __shfl_xor(mh, off));
            float ph = act ? expf(e[h] - mh) : 0.f;
            float sh = ph;
            #pragma unroll
            for (int off = 32; off; off >>= 1) sh += __shfl_xor(sh, off);
            wv[h] = ph / fmaxf(sh, 1e-16f);   // 0 for pad lanes
        }
        if (H == 4) {
            ((float4*)wsh)[lane] = (float4){wv[0], wv[1], wv[2], wv[3]};
        } else {
            wsh[lane] = wv[0];
        }
        __syncthreads();
        // ---- weighted gather, 8-edge unroll, padded to x8 ----
        const float* fl = feat + lane;
        const float* fl2 = feat + 64 + lane;
        bool tail = lane < 8;
        int nb = (deg + 7) & ~7;
        for (int t = 0; t < nb; t += 8) {
            int si[8];
            #pragma unroll
            for (int u = 0; u < 8; ++u) si[u] = ssh[t + u];
            float a[8], b[8];
            #pragma unroll
            for (int u = 0; u < 8; ++u) a[u] = fl[(size_t)si[u] * HID];
            #pragma unroll
            for (int u = 0; u < 8; ++u) b[u] = tail ? fl2[(size_t)si[u] * HID] : 0.f;
            if (H == 4) {
                #pragma unroll
                for (int u = 0; u < 8; ++u) {
                    float4 we = ((const float4*)wsh)[t + u];   // b128 broadcast
                    float wgt[4] = {we.x, we.y, we.z, we.w};
                    #pragma unroll
                    for (int h = 0; h < 4; ++h) {
                        acc[h][0] = fmaf(wgt[h], a[u], acc[h][0]);
                        acc[h][1] = fmaf(wgt[h], b[u], acc[h][1]);
                    }
                }
            } else {
                #pragma unroll
                for (int u = 0; u < 8; ++u) {
                    float wgt = wsh[t + u];
                    acc[0][0] = fmaf(wgt, a[u], acc[0][0]);
                    acc[0][1] = fmaf(wgt, b[u], acc[0][1]);
                }
            }
        }
    } else {
        // ---- generic 3-pass fallback (rare) ----
        float m[H];
        #pragma unroll
        for (int h = 0; h < H; ++h) m[h] = -__builtin_inff();
        for (int i = rp0 + lane; i < rp1; i += 64) {
            int s = csr[i];
            float e[H];
            if (H == 4) {
                float4 lv = ((const float4*)ls)[s];
                e[0] = lv.x; e[1] = lv.y; e[2] = lv.z; e[3] = lv.w;
            } else {
                e[0] = ls[s];
            }
            #pragma unroll
            for (int h = 0; h < H; ++h) {
                float vv = e[h] + ldh[h];
                vv = (vv > 0.f) ? vv : 0.2f * vv;
                m[h] = fmaxf(m[h], vv);
            }
        }
        #pragma unroll
        for (int h = 0; h < H; ++h)
            #pragma unroll
            for (int off = 32; off; off >>= 1) m[h] = fmaxf(m[h], __shfl_xor(m[h], off));

        float ssum[H];
        #pragma unroll
        for (int h = 0; h < H; ++h) ssum[h] = 0.f;
        for (int i = rp0 + lane; i < rp1; i += 64) {
            int s = csr[i];
            float e[H];
            if (H == 4) {
                float4 lv = ((const float4*)ls)[s];
                e[0] = lv.x; e[1] = lv.y; e[2] = lv.z; e[3] = lv.w;
            } else {
                e[0] = ls[s];
            }
            #pragma unroll
            for (int h = 0; h < H; ++h) {
                float vv = e[h] + ldh[h];
                vv = (vv > 0.f) ? vv : 0.2f * vv;
                ssum[h] += expf(vv - m[h]);
            }
        }
        #pragma unroll
        for (int h = 0; h < H; ++h)
            #pragma unroll
            for (int off = 32; off; off >>= 1) ssum[h] += __shfl_xor(ssum[h], off);
        float inv[H];
        #pragma unroll
        for (int h = 0; h < H; ++h) inv[h] = 1.f / fmaxf(ssum[h], 1e-16f);

        for (int base = rp0; base < rp1; base += 64) {
            int i = base + lane;
            int lim = min(64, rp1 - base);
            if (i < rp1) {
                int s = csr[i];
                ssh[lane] = s;
                float e[H];
                if (H == 4) {
                    float4 lv = ((const float4*)ls)[s];
                    e[0] = lv.x; e[1] = lv.y; e[2] = lv.z; e[3] = lv.w;
                } else {
                    e[0] = ls[s];
                }
                #pragma unroll
                for (int h = 0; h < H; ++h) {
                    float vv = e[h] + ldh[h];
                    vv = (vv > 0.f) ? vv : 0.2f * vv;
                    wsh[lane * H + h] = expf(vv - m[h]) * inv[h];
                }
            }
            __syncthreads();
            int t = 0;
            for (; t + 2 <= lim; t += 2) {
                int s0 = ssh[t], s1 = ssh[t + 1];
                const float* r0 = feat + (size_t)s0 * HID;
                const float* r1 = feat + (size_t)s1 * HID;
                float a0 = r0[lane], a1 = r1[lane];
                float b0 = 0.f, b1 = 0.f;
                if (lane < 8) { b0 = r0[64 + lane]; b1 = r1[64 + lane]; }
                #pragma unroll
                for (int h = 0; h < H; ++h) {
                    float w0 = wsh[t * H + h], w1 = wsh[(t + 1) * H + h];
                    acc[h][0] += w0 * a0 + w1 * a1;
                    acc[h][1] += w0 * b0 + w1 * b1;
                }
            }
            if (t < lim) {
                int s0 = ssh[t];
                const float* r0 = feat + (size_t)s0 * HID;
                float a0 = r0[lane];
                float b0 = (lane < 8) ? r0[64 + lane] : 0.f;
                #pragma unroll
                for (int h = 0; h < H; ++h) {
                    float w0 = wsh[t * H + h];
                    acc[h][0] = fmaf(w0, a0, acc[h][0]);
                    acc[h][1] = fmaf(w0, b0, acc[h][1]);
                }
            }
            __syncthreads();
        }
    }

    // ---- common epilogue ----
    #pragma unroll
    for (int h = 0; h < H; ++h) {
        float v0 = acc[h][0], v1 = acc[h][1];
        if (EPI) {
            v0 += bias[lane];
            v0 = (v0 > 0.f) ? v0 : expm1f(v0);
            if (ADD_RES) v0 += res[(size_t)wid * HID + lane];
            if (lane < 8) {
                v1 += bias[64 + lane];
                v1 = (v1 > 0.f) ? v1 : expm1f(v1);
                if (ADD_RES) v1 += res[(size_t)wid * HID + 64 + lane];
            }
        }
        out[(size_t)wid * (H * HID) + h * HID + lane] = v0;
        if (lane < 8) out[(size_t)wid * (H * HID) + h * HID + 64 + lane] = v1;
    }
}

// ---------------------------------------------------------------------------
// Score MLP: out[n] = relu(h[n,:]@Ws1 + bs1) @ Ws2 + bs2.  32 lanes / node.
// ---------------------------------------------------------------------------
__global__ __launch_bounds__(256) void score_kernel(
        const float* __restrict__ h, const float* __restrict__ Ws1, const float* __restrict__ bs1,
        const float* __restrict__ Ws2, const float* __restrict__ bs2,
        float* __restrict__ out, int n) {
    int sub = threadIdx.x >> 5;
    int j = threadIdx.x & 31;
    int node = blockIdx.x * 8 + sub;
    if (node >= n) return;
    const float* row = h + (size_t)node * HID;
    float acc = bs1[j];
    #pragma unroll 8
    for (int c = 0; c < HID; ++c) acc = fmaf(row[c], Ws1[c * 32 + j], acc);
    float v = fmaxf(acc, 0.f) * Ws2[j];
    #pragma unroll
    for (int off = 16; off; off >>= 1) v += __shfl_down(v, off, 32);
    if (j == 0) out[node] = v + bs2[0];
}

// ---------------------------------------------------------------------------
extern "C" void kernel_launch(void* const* d_in, const int* in_sizes, int n_in,
                              void* d_out, int out_size, void* d_ws, size_t ws_size,
                              hipStream_t stream) {
    const float* x      = (const float*)d_in[0];
    const int*   ei     = (const int*)  d_in[1];
    const float* W_in   = (const float*)d_in[2];
    const float* b_in   = (const float*)d_in[3];
    const float* W1     = (const float*)d_in[4];
    const float* a_src1 = (const float*)d_in[5];
    const float* a_dst1 = (const float*)d_in[6];
    const float* b1     = (const float*)d_in[7];
    const float* W2     = (const float*)d_in[8];
    const float* a_src2 = (const float*)d_in[9];
    const float* a_dst2 = (const float*)d_in[10];
    const float* b2     = (const float*)d_in[11];
    const float* W3     = (const float*)d_in[12];
    const float* a_src3 = (const float*)d_in[13];
    const float* a_dst3 = (const float*)d_in[14];
    const float* b3     = (const float*)d_in[15];
    const float* Ws1    = (const float*)d_in[16];
    const float* bs1    = (const float*)d_in[17];
    const float* Ws2    = (const float*)d_in[18];
    const float* bs2    = (const float*)d_in[19];
    float* out = (float*)d_out;

    // workspace carve-up (deg+cursor adjacent -> one memset)
    float* ws    = (float*)d_ws;
    float* x0    = ws;                        // N*72
    float* bufA  = x0 + (size_t)NN * HID;     // N*288 (agg1 / hp2 / hp3)
    float* bufB  = bufA + (size_t)NN * 288;   // N*288 (h1 / h2 / h3)
    float* ls    = bufB + (size_t)NN * 288;   // N*4
    float* ld    = ls + (size_t)NN * 4;       // N*4
    float* wsrc1 = ld + (size_t)NN * 4;       // 288
    float* wdst1 = wsrc1 + 288;               // 288
    int* deg    = (int*)(wdst1 + 288);        // N
    int* cursor = deg + NN;                   // N (adjacent to deg)
    int* rowptr = cursor + NN;                // N+1
    int* tmp    = rowptr + NN + 1;            // N
    int* bsum   = tmp + NN;                   // 256
    int* csr    = bsum + 256;                 // ET
    uintptr_t bp = ((uintptr_t)(csr + ET) + 15) & ~(uintptr_t)15;
    short* BtInH = (short*)bp;                // 72*256
    short* BtInL = BtInH + 18432;
    short* Bt1H  = BtInL + 18432;             // 4*72*72
    short* Bt1L  = Bt1H + 20736;
    short* Bt2H  = Bt1L + 20736;              // 72*288
    short* Bt2L  = Bt2H + 20736;
    short* Bt3H  = Bt2L + 20736;              // 72*72
    short* Bt3L  = Bt3H + 5184;

    hipMemsetAsync(deg, 0, 2 * NN * sizeof(int), stream);   // deg + cursor

    const int egrid = (ET + 255) / 256;
    const int sgrid = (NN + 255) / 256;
    hist_kernel<<<egrid, 256, 0, stream>>>(ei, deg);
    scan1_kernel<<<sgrid, 256, 0, stream>>>(deg, tmp, bsum, NN);
    scan2_kernel<<<1, 256, 0, stream>>>(bsum, sgrid);
    scan3_kernel<<<sgrid, 256, 0, stream>>>(tmp, bsum, rowptr, NN);
    scatter_kernel<<<egrid, 256, 0, stream>>>(ei, rowptr, cursor, csr);

    prep_kernel<<<(PRTOT + 255) / 256, 256, 0, stream>>>(
        W_in, W1, W2, W3, a_src1, a_dst1,
        BtInH, BtInL, Bt1H, Bt1L, Bt2H, Bt2L, Bt3H, Bt3L, wsrc1, wdst1);

    const int mblocks = (NN + 63) / 64;   // 782
    // x0 = x @ W_in + b_in, fused layer-1 logits (4 heads via projections)
    gemm_mfma<4, false, false><<<dim3(mblocks, 1), 256, 0, stream>>>(
        x, BtInH, BtInL, b_in, x0, wsrc1, wdst1, ls, ld, NN, IN_DIM, IN_DIM, HID);
    // ---- layer 1 (aggregate in input space, then per-head GEMM + ELU) ----
    agg_gather<4, false, false><<<NN, 64, 0, stream>>>(
        x0, ls, ld, rowptr, csr, nullptr, nullptr, bufA, NN);
    gemm_mfma<0, true, true><<<dim3(mblocks, 4), 256, 0, stream>>>(
        bufA, Bt1H, Bt1L, b1, bufB, nullptr, nullptr, nullptr, nullptr, NN, HID, 288, 288);
    // ---- layer 2 ----
    gemm_mfma<1, false, false><<<dim3(mblocks, 1), 256, 0, stream>>>(
        bufB, Bt2H, Bt2L, nullptr, bufA, a_src2, a_dst2, ls, ld, NN, 288, 288, HID);
    agg_gather<1, true, false><<<NN, 64, 0, stream>>>(
        bufA, ls, ld, rowptr, csr, b2, nullptr, bufB, NN);
    // ---- layer 3 ----
    gemm_mfma<1, false, false><<<dim3(mblocks, 1), 256, 0, stream>>>(
        bufB, Bt3H, Bt3L, nullptr, bufA, a_src3, a_dst3, ls, ld, NN, HID, HID, HID);
    agg_gather<1, true, true><<<NN, 64, 0, stream>>>(
        bufA, ls, ld, rowptr, csr, b3, x0, bufB, NN);
    // ---- score head ----
    score_kernel<<<(NN + 7) / 8, 256, 0, stream>>>(bufB, Ws1, bs1, Ws2, bs2, out, NN);
}

// Round 12
// 464.977 us; speedup vs baseline: 1.0517x; 1.0201x over previous
//
#include <hip/hip_runtime.h>
#include <cmath>

// Problem constants (match reference setup_inputs)
#define NN 50000
#define EE 800000
#define ET (EE + NN)   // edges + self loops
#define IN_DIM 256
#define HID 72

typedef __attribute__((ext_vector_type(8))) short s8v;   // bf16 x8 MFMA frag
typedef __attribute__((ext_vector_type(4))) short s4v;
typedef __attribute__((ext_vector_type(4))) float f4v;   // MFMA acc

__device__ __forceinline__ ushort f2bf(float x) {
    uint u = __float_as_uint(x);
    return (ushort)((u + 0x7fffu + ((u >> 16) & 1u)) >> 16);   // RNE
}
__device__ __forceinline__ float bf2f(ushort h) {
    return __uint_as_float(((uint)h) << 16);
}
__device__ __forceinline__ void split4(const float4& v, s4v& h, s4v& l) {
    ushort h0 = f2bf(v.x), h1 = f2bf(v.y), h2 = f2bf(v.z), h3 = f2bf(v.w);
    h = (s4v){(short)h0, (short)h1, (short)h2, (short)h3};
    l = (s4v){(short)f2bf(v.x - bf2f(h0)), (short)f2bf(v.y - bf2f(h1)),
              (short)f2bf(v.z - bf2f(h2)), (short)f2bf(v.w - bf2f(h3))};
}
__device__ __forceinline__ f4v mfma16(s8v a, s8v b, f4v c) {
    return __builtin_amdgcn_mfma_f32_16x16x32_bf16(a, b, c, 0, 0, 0);
}

// ---------------------------------------------------------------------------
// CSR construction: histogram -> hierarchical scan -> scatter
// ---------------------------------------------------------------------------
__global__ void hist_kernel(const int* __restrict__ ei, int* __restrict__ deg) {
    int i = blockIdx.x * blockDim.x + threadIdx.x;
    if (i >= ET) return;
    int dst = (i < EE) ? ei[EE + i] : (i - EE);
    atomicAdd(&deg[dst], 1);
}

__global__ __launch_bounds__(256) void scan1_kernel(const int* __restrict__ deg,
        int* __restrict__ tmp, int* __restrict__ bsum, int n) {
    __shared__ int sh[256];
    int tid = threadIdx.x;
    int i = blockIdx.x * 256 + tid;
    sh[tid] = (i < n) ? deg[i] : 0;
    __syncthreads();
    for (int off = 1; off < 256; off <<= 1) {
        int t = (tid >= off) ? sh[tid - off] : 0;
        __syncthreads();
        sh[tid] += t;
        __syncthreads();
    }
    if (i < n) tmp[i] = sh[tid];
    if (tid == 255) bsum[blockIdx.x] = sh[255];
}

__global__ __launch_bounds__(256) void scan2_kernel(int* __restrict__ bsum, int nb) {
    __shared__ int sh[256];
    int tid = threadIdx.x;
    sh[tid] = (tid < nb) ? bsum[tid] : 0;
    __syncthreads();
    for (int off = 1; off < 256; off <<= 1) {
        int t = (tid >= off) ? sh[tid - off] : 0;
        __syncthreads();
        sh[tid] += t;
        __syncthreads();
    }
    if (tid < nb) bsum[tid] = sh[tid];
}

__global__ __launch_bounds__(256) void scan3_kernel(const int* __restrict__ tmp,
        const int* __restrict__ bsum, int* __restrict__ rowptr, int n) {
    int i = blockIdx.x * 256 + threadIdx.x;
    if (i == 0) rowptr[0] = 0;
    if (i < n) {
        int off = (blockIdx.x > 0) ? bsum[blockIdx.x - 1] : 0;
        rowptr[i + 1] = tmp[i] + off;
    }
}

__global__ void scatter_kernel(const int* __restrict__ ei, const int* __restrict__ rowptr,
                               int* __restrict__ cursor, int* __restrict__ csr) {
    int i = blockIdx.x * blockDim.x + threadIdx.x;
    if (i >= ET) return;
    int src = (i < EE) ? ei[i] : (i - EE);
    int dst = (i < EE) ? ei[EE + i] : (i - EE);
    int pos = atomicAdd(&cursor[dst], 1);
    csr[rowptr[dst] + pos] = src;
}

// ---------------------------------------------------------------------------
// Fused prep: split+transpose all 4 weights to (hi,lo) bf16 Bt[h][n][k],
// plus layer-1 projected attention vectors.  One dispatch.
// ---------------------------------------------------------------------------
__device__ __forceinline__ void wsplit_one(const float* W, int ldw, int K,
        int idx, short* outH, short* outL) {
    int h = idx / (72 * K);
    int rem = idx - h * 72 * K;
    int n = rem / K, k = rem - n * K;
    float v = W[(size_t)k * ldw + h * 72 + n];
    ushort hi = f2bf(v);
    outH[idx] = (short)hi;
    outL[idx] = (short)f2bf(v - bf2f(hi));
}

#define PR0 18432            // W_in  (K=256, NH=1, ldw=72)
#define PR1 (PR0 + 20736)    // W1    (K=72,  NH=4, ldw=288)
#define PR2 (PR1 + 20736)    // W2    (K=288, NH=1, ldw=72)
#define PR3 (PR2 + 5184)     // W3    (K=72,  NH=1, ldw=72)
#define PRTOT (PR3 + 288)    // attnproj (288)

__global__ __launch_bounds__(256) void prep_kernel(
        const float* __restrict__ W_in, const float* __restrict__ W1,
        const float* __restrict__ W2, const float* __restrict__ W3,
        const float* __restrict__ a_src, const float* __restrict__ a_dst,
        short* __restrict__ BtInH, short* __restrict__ BtInL,
        short* __restrict__ Bt1H, short* __restrict__ Bt1L,
        short* __restrict__ Bt2H, short* __restrict__ Bt2L,
        short* __restrict__ Bt3H, short* __restrict__ Bt3L,
        float* __restrict__ wsrc, float* __restrict__ wdst) {
    int gid = blockIdx.x * 256 + threadIdx.x;
    if (gid < PR0) {
        wsplit_one(W_in, 72, 256, gid, BtInH, BtInL);
    } else if (gid < PR1) {
        wsplit_one(W1, 288, 72, gid - PR0, Bt1H, Bt1L);
    } else if (gid < PR2) {
        wsplit_one(W2, 72, 288, gid - PR1, Bt2H, Bt2L);
    } else if (gid < PR3) {
        wsplit_one(W3, 72, 72, gid - PR2, Bt3H, Bt3L);
    } else if (gid < PRTOT) {
        int j = gid - PR3;                 // j = h*72 + k
        int h = j / HID, k = j % HID;
        const float* wrow = W1 + (size_t)k * (4 * HID) + h * HID;
        const float* as = a_src + h * HID;
        const float* ad = a_dst + h * HID;
        float s = 0.f, d = 0.f;
        for (int c = 0; c < HID; ++c) {
            float w = wrow[c];
            s = fmaf(w, as[c], s);
            d = fmaf(w, ad[c], d);
        }
        wsrc[j] = s;
        wdst[j] = d;
    }
}

// ---------------------------------------------------------------------------
// Split-bf16 MFMA GEMM with register-prefetch double buffering.
// Single LDS buffer, two barriers/tile (ping-pong regressed: round 10).
// C[M,72] = A[M,K] @ B[K,72] (+bias)(+ELU)(+logits)(+packed-bf16 copy).
// PACKOUT: epilogue also writes Cp[gr*36 + col/2] = bf16(col)|bf16(col+1)<<16
// via neighbor-lane shfl (even/odd column pairing) — feeds the packed gather.
// ---------------------------------------------------------------------------
template <int NLOGIT, bool ELU_EPI, bool BATCHED, bool PACKOUT>
__global__ __launch_bounds__(256) void gemm_mfma(
        const float* __restrict__ A, const short* __restrict__ BtH,
        const short* __restrict__ BtL, const float* __restrict__ bias,
        float* __restrict__ C, uint* __restrict__ Cp,
        const float* __restrict__ lvs, const float* __restrict__ lvd,
        float* __restrict__ ls, float* __restrict__ ld,
        int M, int K, int lda, int Nfull) {
    __shared__ __align__(16) short AhS[64 * 40], AlS[64 * 40];   // [m][k] pad 40
    __shared__ __align__(16) short BhS[80 * 40], BlS[80 * 40];   // [n][k] pad 40

    int tid = threadIdx.x;
    int row0 = blockIdx.x * 64;
    int hh = BATCHED ? blockIdx.y : 0;
    int aoff = BATCHED ? hh * 72 : 0;
    int coff = BATCHED ? hh * 72 : 0;
    const short* bhg = BtH + (size_t)hh * 72 * K;
    const short* blg = BtL + (size_t)hh * 72 * K;

    for (int i = tid; i < 8 * 40; i += 256) {
        BhS[72 * 40 + i] = 0;
        BlS[72 * 40 + i] = 0;
    }

    int w = tid >> 6;
    int lane = tid & 63;
    int q = lane >> 4, l16 = lane & 15;

    f4v acc[5];
    #pragma unroll
    for (int f = 0; f < 5; ++f) acc[f] = (f4v)0.f;

    int ar = tid >> 2;
    int aseg = tid & 3;
    bool arok = (row0 + ar) < M;
    const float* aptr = A + (size_t)(row0 + ar) * lda + aoff;
    int bn0 = tid >> 2, bq0 = tid & 3;
    int bn1 = (tid + 256) >> 2;

    float4 va, vb;
    s8v bh0, bl0, bh1, bl1;
    auto gload = [&](int k0) {
        va = (float4){0, 0, 0, 0};
        vb = (float4){0, 0, 0, 0};
        int ka = k0 + aseg * 8;
        if (arok && ka < K)     va = *(const float4*)(aptr + ka);
        if (arok && ka + 4 < K) vb = *(const float4*)(aptr + ka + 4);
        bh0 = (s8v)0; bl0 = (s8v)0;
        int kb = k0 + bq0 * 8;
        if (kb < K) {
            bh0 = *(const s8v*)(bhg + (size_t)bn0 * K + kb);
            bl0 = *(const s8v*)(blg + (size_t)bn0 * K + kb);
        }
        bh1 = (s8v)0; bl1 = (s8v)0;
        if (tid < 32 && kb < K) {
            bh1 = *(const s8v*)(bhg + (size_t)bn1 * K + kb);
            bl1 = *(const s8v*)(blg + (size_t)bn1 * K + kb);
        }
    };
    auto commit = [&]() {
        s4v h0, l0, h1, l1;
        split4(va, h0, l0);
        split4(vb, h1, l1);
        *(s4v*)&AhS[ar * 40 + aseg * 8]     = h0;
        *(s4v*)&AhS[ar * 40 + aseg * 8 + 4] = h1;
        *(s4v*)&AlS[ar * 40 + aseg * 8]     = l0;
        *(s4v*)&AlS[ar * 40 + aseg * 8 + 4] = l1;
        *(s8v*)&BhS[bn0 * 40 + bq0 * 8] = bh0;
        *(s8v*)&BlS[bn0 * 40 + bq0 * 8] = bl0;
        if (tid < 32) {
            *(s8v*)&BhS[bn1 * 40 + bq0 * 8] = bh1;
            *(s8v*)&BlS[bn1 * 40 + bq0 * 8] = bl1;
        }
    };

    int ntiles = (K + 31) / 32;
    gload(0);
    for (int t = 0; t < ntiles; ++t) {
        commit();
        __syncthreads();
        if (t + 1 < ntiles) gload((t + 1) * 32);
        s8v ah = *(const s8v*)&AhS[(w * 16 + l16) * 40 + q * 8];
        s8v al = *(const s8v*)&AlS[(w * 16 + l16) * 40 + q * 8];
        #pragma unroll
        for (int f = 0; f < 5; ++f) {
            s8v bh = *(const s8v*)&BhS[(f * 16 + l16) * 40 + q * 8];
            s8v bl = *(const s8v*)&BlS[(f * 16 + l16) * 40 + q * 8];
            acc[f] = mfma16(ah, bh, acc[f]);
            acc[f] = mfma16(ah, bl, acc[f]);
            acc[f] = mfma16(al, bh, acc[f]);
        }
        __syncthreads();
    }

    float v[5][4];
    #pragma unroll
    for (int f = 0; f < 5; ++f) {
        int col = f * 16 + l16;
        bool cv = col < 72;
        #pragma unroll
        for (int r = 0; r < 4; ++r) {
            float t = acc[f][r];
            if (cv && bias) t += bias[coff + col];
            if (ELU_EPI) t = (t > 0.f) ? t : expm1f(t);
            v[f][r] = cv ? t : 0.f;
        }
    }
    if (NLOGIT > 0) {
        #pragma unroll
        for (int h2 = 0; h2 < NLOGIT; ++h2) {
            #pragma unroll
            for (int r = 0; r < 4; ++r) {
                float s = 0.f, d = 0.f;
                #pragma unroll
                for (int f = 0; f < 5; ++f) {
                    int col = f * 16 + l16;
                    float lw = (col < 72) ? lvs[h2 * 72 + col] : 0.f;
                    float dw = (col < 72) ? lvd[h2 * 72 + col] : 0.f;
                    s = fmaf(v[f][r], lw, s);
                    d = fmaf(v[f][r], dw, d);
                }
                s += __shfl_xor(s, 1); s += __shfl_xor(s, 2);
                s += __shfl_xor(s, 4); s += __shfl_xor(s, 8);
                d += __shfl_xor(d, 1); d += __shfl_xor(d, 2);
                d += __shfl_xor(d, 4); d += __shfl_xor(d, 8);
                int gr = row0 + w * 16 + q * 4 + r;
                if (l16 == 0 && gr < M) {
                    ls[gr * NLOGIT + h2] = s;
                    ld[gr * NLOGIT + h2] = d;
                }
            }
        }
    }
    if (PACKOUT) {
        // even/odd column pairing via neighbor-lane shfl (lane^1 flips l16 bit0)
        #pragma unroll
        for (int f = 0; f < 5; ++f) {
            int col = f * 16 + l16;
            #pragma unroll
            for (int r = 0; r < 4; ++r) {
                float vo = __shfl_xor(v[f][r], 1);
                if ((l16 & 1) == 0 && col < 72) {
                    int gr = row0 + w * 16 + q * 4 + r;
                    if (gr < M) {
                        uint u = ((uint)f2bf(vo) << 16) | (uint)f2bf(v[f][r]);
                        Cp[(size_t)gr * 36 + (col >> 1)] = u;
                    }
                }
            }
        }
    }
    #pragma unroll
    for (int f = 0; f < 5; ++f) {
        int col = f * 16 + l16;
        if (col >= 72) continue;
        #pragma unroll
        for (int r = 0; r < 4; ++r) {
            int gr = row0 + w * 16 + q * 4 + r;
            if (gr < M) C[(size_t)gr * Nfull + coff + col] = v[f][r];
        }
    }
}

// ---------------------------------------------------------------------------
// Softmax-weighted gather; one wave per dst node.  deg<=64 fast path:
// merged softmax sweep + 8-edge-unrolled gather.  PACKED variant gathers
// bf16-pair rows (144 B vs 288 B — working set 7.2 MB, ~2x L2 hit rate);
// lane<36 owns channels {2*lane, 2*lane+1}.
// ---------------------------------------------------------------------------
template <int H, bool EPI, bool ADD_RES, bool PACKED>
__global__ __launch_bounds__(64) void agg_gather(
        const float* __restrict__ feat, const uint* __restrict__ featp,
        const float* __restrict__ ls, const float* __restrict__ ld,
        const int* __restrict__ rowptr, const int* __restrict__ csr,
        const float* __restrict__ bias, const float* __restrict__ res,
        float* __restrict__ out, int n) {
    __shared__ float wsh[64 * H];
    __shared__ int ssh[64];
    int wid = blockIdx.x;
    int lane = threadIdx.x;
    int rp0 = rowptr[wid], rp1 = rowptr[wid + 1];
    int deg = rp1 - rp0;

    float ldh[H];
    if (H == 4) {
        float4 t = ((const float4*)ld)[wid];
        ldh[0] = t.x; ldh[1] = t.y; ldh[2] = t.z; ldh[3] = t.w;
    } else {
        ldh[0] = ld[wid];
    }

    float acc[H][2];
    #pragma unroll
    for (int h = 0; h < H; ++h) { acc[h][0] = 0.f; acc[h][1] = 0.f; }

    if (deg <= 64) {
        // ---- merged softmax sweep: one edge per lane (clamped for pad) ----
        bool act = lane < deg;
        int s = csr[rp0 + (act ? lane : 0)];
        ssh[lane] = s;
        float e[H];
        float ev[H];
        if (H == 4) {
            float4 lv = ((const float4*)ls)[s];
            ev[0] = lv.x; ev[1] = lv.y; ev[2] = lv.z; ev[3] = lv.w;
        } else {
            ev[0] = ls[s];
        }
        #pragma unroll
        for (int h = 0; h < H; ++h) {
            float vv = ev[h] + ldh[h];
            vv = (vv > 0.f) ? vv : 0.2f * vv;
            e[h] = act ? vv : -__builtin_inff();
        }
        float wv[H];
        #pragma unroll
        for (int h = 0; h < H; ++h) {
            float mh = e[h];
            #pragma unroll
            for (int off = 32; off; off >>= 1) mh = fmaxf(mh, __shfl_xor(mh, off));
            float ph = act ? expf(e[h] - mh) : 0.f;
            float sh = ph;
            #pragma unroll
            for (int off = 32; off; off >>= 1) sh += __shfl_xor(sh, off);
            wv[h] = ph / fmaxf(sh, 1e-16f);
        }
        if (H == 4) {
            ((float4*)wsh)[lane] = (float4){wv[0], wv[1], wv[2], wv[3]};
        } else {
            wsh[lane] = wv[0];
        }
        __syncthreads();

        int nb = (deg + 7) & ~7;
        if (PACKED) {
            const uint* rowbase = featp + (lane < 36 ? lane : 0);
            for (int t = 0; t < nb; t += 8) {
                int si[8];
                #pragma unroll
                for (int u = 0; u < 8; ++u) si[u] = ssh[t + u];
                uint pv[8];
                #pragma unroll
                for (int u = 0; u < 8; ++u) pv[u] = rowbase[(size_t)si[u] * 36];
                #pragma unroll
                for (int u = 0; u < 8; ++u) {
                    float c0 = bf2f((ushort)(pv[u] & 0xffffu));
                    float c1 = bf2f((ushort)(pv[u] >> 16));
                    if (H == 4) {
                        float4 we = ((const float4*)wsh)[t + u];
                        float wgt[4] = {we.x, we.y, we.z, we.w};
                        #pragma unroll
                        for (int h = 0; h < 4; ++h) {
                            acc[h][0] = fmaf(wgt[h], c0, acc[h][0]);
                            acc[h][1] = fmaf(wgt[h], c1, acc[h][1]);
                        }
                    } else {
                        float wgt = wsh[t + u];
                        acc[0][0] = fmaf(wgt, c0, acc[0][0]);
                        acc[0][1] = fmaf(wgt, c1, acc[0][1]);
                    }
                }
            }
        } else {
            const float* fl = feat + lane;
            const float* fl2 = feat + 64 + lane;
            bool tail = lane < 8;
            for (int t = 0; t < nb; t += 8) {
                int si[8];
                #pragma unroll
                for (int u = 0; u < 8; ++u) si[u] = ssh[t + u];
                float a[8], b[8];
                #pragma unroll
                for (int u = 0; u < 8; ++u) a[u] = fl[(size_t)si[u] * HID];
                #pragma unroll
                for (int u = 0; u < 8; ++u) b[u] = tail ? fl2[(size_t)si[u] * HID] : 0.f;
                if (H == 4) {
                    #pragma unroll
                    for (int u = 0; u < 8; ++u) {
                        float4 we = ((const float4*)wsh)[t + u];
                        float wgt[4] = {we.x, we.y, we.z, we.w};
                        #pragma unroll
                        for (int h = 0; h < 4; ++h) {
                            acc[h][0] = fmaf(wgt[h], a[u], acc[h][0]);
                            acc[h][1] = fmaf(wgt[h], b[u], acc[h][1]);
                        }
                    }
                } else {
                    #pragma unroll
                    for (int u = 0; u < 8; ++u) {
                        float wgt = wsh[t + u];
                        acc[0][0] = fmaf(wgt, a[u], acc[0][0]);
                        acc[0][1] = fmaf(wgt, b[u], acc[0][1]);
                    }
                }
            }
        }
    } else {
        // ---- generic 3-pass fallback (rare) ----
        float m[H];
        #pragma unroll
        for (int h = 0; h < H; ++h) m[h] = -__builtin_inff();
        for (int i = rp0 + lane; i < rp1; i += 64) {
            int s = csr[i];
            float e[H];
            if (H == 4) {
                float4 lv = ((const float4*)ls)[s];
                e[0] = lv.x; e[1] = lv.y; e[2] = lv.z; e[3] = lv.w;
            } else {
                e[0] = ls[s];
            }
            #pragma unroll
            for (int h = 0; h < H; ++h) {
                float vv = e[h] + ldh[h];
                vv = (vv > 0.f) ? vv : 0.2f * vv;
                m[h] = fmaxf(m[h], vv);
            }
        }
        #pragma unroll
        for (int h = 0; h < H; ++h)
            #pragma unroll
            for (int off = 32; off; off >>= 1) m[h] = fmaxf(m[h], __shfl_xor(m[h], off));

        float ssum[H];
        #pragma unroll
        for (int h = 0; h < H; ++h) ssum[h] = 0.f;
        for (int i = rp0 + lane; i < rp1; i += 64) {
            int s = csr[i];
            float e[H];
            if (H == 4) {
                float4 lv = ((const float4*)ls)[s];
                e[0] = lv.x; e[1] = lv.y; e[2] = lv.z; e[3] = lv.w;
            } else {
                e[0] = ls[s];
            }
            #pragma unroll
            for (int h = 0; h < H; ++h) {
                float vv = e[h] + ldh[h];
                vv = (vv > 0.f) ? vv : 0.2f * vv;
                ssum[h] += expf(vv - m[h]);
            }
        }
        #pragma unroll
        for (int h = 0; h < H; ++h)
            #pragma unroll
            for (int off = 32; off; off >>= 1) ssum[h] += __shfl_xor(ssum[h], off);
        float inv[H];
        #pragma unroll
        for (int h = 0; h < H; ++h) inv[h] = 1.f / fmaxf(ssum[h], 1e-16f);

        for (int base = rp0; base < rp1; base += 64) {
            int i = base + lane;
            int lim = min(64, rp1 - base);
            if (i < rp1) {
                int s = csr[i];
                ssh[lane] = s;
                float e[H];
                if (H == 4) {
                    float4 lv = ((const float4*)ls)[s];
                    e[0] = lv.x; e[1] = lv.y; e[2] = lv.z; e[3] = lv.w;
                } else {
                    e[0] = ls[s];
                }
                if (H == 4) {
                    float p0 = expf(((e[0] + ldh[0] > 0.f) ? e[0] + ldh[0] : 0.2f * (e[0] + ldh[0])) - m[0]) * inv[0];
                    float p1 = expf(((e[1] + ldh[1] > 0.f) ? e[1] + ldh[1] : 0.2f * (e[1] + ldh[1])) - m[1]) * inv[1];
                    float p2 = expf(((e[2] + ldh[2] > 0.f) ? e[2] + ldh[2] : 0.2f * (e[2] + ldh[2])) - m[2]) * inv[2];
                    float p3 = expf(((e[3] + ldh[3] > 0.f) ? e[3] + ldh[3] : 0.2f * (e[3] + ldh[3])) - m[3]) * inv[3];
                    ((float4*)wsh)[lane] = (float4){p0, p1, p2, p3};
                } else {
                    float vv = e[0] + ldh[0];
                    vv = (vv > 0.f) ? vv : 0.2f * vv;
                    wsh[lane] = expf(vv - m[0]) * inv[0];
                }
            }
            __syncthreads();
            for (int t = 0; t < lim; ++t) {
                float c0, c1;
                if (PACKED) {
                    uint pv = featp[(size_t)ssh[t] * 36 + (lane < 36 ? lane : 0)];
                    c0 = bf2f((ushort)(pv & 0xffffu));
                    c1 = bf2f((ushort)(pv >> 16));
                } else {
                    const float* r0 = feat + (size_t)ssh[t] * HID;
                    c0 = r0[lane];
                    c1 = (lane < 8) ? r0[64 + lane] : 0.f;
                }
                if (H == 4) {
                    float4 we = ((const float4*)wsh)[t];
                    float wgt[4] = {we.x, we.y, we.z, we.w};
                    #pragma unroll
                    for (int h = 0; h < 4; ++h) {
                        acc[h][0] = fmaf(wgt[h], c0, acc[h][0]);
                        acc[h][1] = fmaf(wgt[h], c1, acc[h][1]);
                    }
                } else {
                    float wgt = wsh[t];
                    acc[0][0] = fmaf(wgt, c0, acc[0][0]);
                    acc[0][1] = fmaf(wgt, c1, acc[0][1]);
                }
            }
            __syncthreads();
        }
    }

    // ---- epilogue ----
    if (PACKED) {
        // lane<36 owns channels {2*lane, 2*lane+1}; EPI unused on this path
        if (lane < 36) {
            #pragma unroll
            for (int h = 0; h < H; ++h) {
                *(float2*)&out[(size_t)wid * (H * HID) + h * HID + 2 * lane] =
                    (float2){acc[h][0], acc[h][1]};
            }
        }
    } else {
        #pragma unroll
        for (int h = 0; h < H; ++h) {
            float v0 = acc[h][0], v1 = acc[h][1];
            if (EPI) {
                v0 += bias[lane];
                v0 = (v0 > 0.f) ? v0 : expm1f(v0);
                if (ADD_RES) v0 += res[(size_t)wid * HID + lane];
                if (lane < 8) {
                    v1 += bias[64 + lane];
                    v1 = (v1 > 0.f) ? v1 : expm1f(v1);
                    if (ADD_RES) v1 += res[(size_t)wid * HID + 64 + lane];
                }
            }
            out[(size_t)wid * (H * HID) + h * HID + lane] = v0;
            if (lane < 8) out[(size_t)wid * (H * HID) + h * HID + 64 + lane] = v1;
        }
    }
}

// ---------------------------------------------------------------------------
// Score MLP: out[n] = relu(h[n,:]@Ws1 + bs1) @ Ws2 + bs2.  32 lanes / node.
// ---------------------------------------------------------------------------
__global__ __launch_bounds__(256) void score_kernel(
        const float* __restrict__ h, const float* __restrict__ Ws1, const float* __restrict__ bs1,
        const float* __restrict__ Ws2, const float* __restrict__ bs2,
        float* __restrict__ out, int n) {
    int sub = threadIdx.x >> 5;
    int j = threadIdx.x & 31;
    int node = blockIdx.x * 8 + sub;
    if (node >= n) return;
    const float* row = h + (size_t)node * HID;
    float acc = bs1[j];
    #pragma unroll 8
    for (int c = 0; c < HID; ++c) acc = fmaf(row[c], Ws1[c * 32 + j], acc);
    float v = fmaxf(acc, 0.f) * Ws2[j];
    #pragma unroll
    for (int off = 16; off; off >>= 1) v += __shfl_down(v, off, 32);
    if (j == 0) out[node] = v + bs2[0];
}

// ---------------------------------------------------------------------------
extern "C" void kernel_launch(void* const* d_in, const int* in_sizes, int n_in,
                              void* d_out, int out_size, void* d_ws, size_t ws_size,
                              hipStream_t stream) {
    const float* x      = (const float*)d_in[0];
    const int*   ei     = (const int*)  d_in[1];
    const float* W_in   = (const float*)d_in[2];
    const float* b_in   = (const float*)d_in[3];
    const float* W1     = (const float*)d_in[4];
    const float* a_src1 = (const float*)d_in[5];
    const float* a_dst1 = (const float*)d_in[6];
    const float* b1     = (const float*)d_in[7];
    const float* W2     = (const float*)d_in[8];
    const float* a_src2 = (const float*)d_in[9];
    const float* a_dst2 = (const float*)d_in[10];
    const float* b2     = (const float*)d_in[11];
    const float* W3     = (const float*)d_in[12];
    const float* a_src3 = (const float*)d_in[13];
    const float* a_dst3 = (const float*)d_in[14];
    const float* b3     = (const float*)d_in[15];
    const float* Ws1    = (const float*)d_in[16];
    const float* bs1    = (const float*)d_in[17];
    const float* Ws2    = (const float*)d_in[18];
    const float* bs2    = (const float*)d_in[19];
    float* out = (float*)d_out;

    // workspace carve-up (deg+cursor adjacent -> one memset)
    float* ws    = (float*)d_ws;
    float* x0    = ws;                        // N*72
    float* bufA  = x0 + (size_t)NN * HID;     // N*288 (agg1 / hp2 / hp3)
    float* bufB  = bufA + (size_t)NN * 288;   // N*288 (h1 / h2 / h3)
    float* ls    = bufB + (size_t)NN * 288;   // N*4
    float* ld    = ls + (size_t)NN * 4;       // N*4
    float* wsrc1 = ld + (size_t)NN * 4;       // 288
    float* wdst1 = wsrc1 + 288;               // 288
    int* deg    = (int*)(wdst1 + 288);        // N
    int* cursor = deg + NN;                   // N (adjacent to deg)
    int* rowptr = cursor + NN;                // N+1
    int* tmp    = rowptr + NN + 1;            // N
    int* bsum   = tmp + NN;                   // 256
    int* csr    = bsum + 256;                 // ET
    uintptr_t bp = ((uintptr_t)(csr + ET) + 15) & ~(uintptr_t)15;
    short* BtInH = (short*)bp;                // 72*256
    short* BtInL = BtInH + 18432;
    short* Bt1H  = BtInL + 18432;             // 4*72*72
    short* Bt1L  = Bt1H + 20736;
    short* Bt2H  = Bt1L + 20736;              // 72*288
    short* Bt2L  = Bt2H + 20736;
    short* Bt3H  = Bt2L + 20736;              // 72*72
    short* Bt3L  = Bt3H + 5184;
    uint*  x0p   = (uint*)(Bt3L + 5184);      // N*36 packed bf16 pairs

    hipMemsetAsync(deg, 0, 2 * NN * sizeof(int), stream);   // deg + cursor

    const int egrid = (ET + 255) / 256;
    const int sgrid = (NN + 255) / 256;
    hist_kernel<<<egrid, 256, 0, stream>>>(ei, deg);
    scan1_kernel<<<sgrid, 256, 0, stream>>>(deg, tmp, bsum, NN);
    scan2_kernel<<<1, 256, 0, stream>>>(bsum, sgrid);
    scan3_kernel<<<sgrid, 256, 0, stream>>>(tmp, bsum, rowptr, NN);
    scatter_kernel<<<egrid, 256, 0, stream>>>(ei, rowptr, cursor, csr);

    prep_kernel<<<(PRTOT + 255) / 256, 256, 0, stream>>>(
        W_in, W1, W2, W3, a_src1, a_dst1,
        BtInH, BtInL, Bt1H, Bt1L, Bt2H, Bt2L, Bt3H, Bt3L, wsrc1, wdst1);

    const int mblocks = (NN + 63) / 64;   // 782
    // x0 = x @ W_in + b_in, fused layer-1 logits + packed bf16 copy
    gemm_mfma<4, false, false, true><<<dim3(mblocks, 1), 256, 0, stream>>>(
        x, BtInH, BtInL, b_in, x0, x0p, wsrc1, wdst1, ls, ld, NN, IN_DIM, IN_DIM, HID);
    // ---- layer 1: packed gather in input space, then per-head GEMM + ELU --
    agg_gather<4, false, false, true><<<NN, 64, 0, stream>>>(
        nullptr, x0p, ls, ld, rowptr, csr, nullptr, nullptr, bufA, NN);
    gemm_mfma<0, true, true, false><<<dim3(mblocks, 4), 256, 0, stream>>>(
        bufA, Bt1H, Bt1L, b1, bufB, nullptr, nullptr, nullptr, nullptr, nullptr,
        NN, HID, 288, 288);
    // ---- layer 2 ----
    gemm_mfma<1, false, false, false><<<dim3(mblocks, 1), 256, 0, stream>>>(
        bufB, Bt2H, Bt2L, nullptr, bufA, nullptr, a_src2, a_dst2, ls, ld,
        NN, 288, 288, HID);
    agg_gather<1, true, false, false><<<NN, 64, 0, stream>>>(
        bufA, nullptr, ls, ld, rowptr, csr, b2, nullptr, bufB, NN);
    // ---- layer 3 ----
    gemm_mfma<1, false, false, false><<<dim3(mblocks, 1), 256, 0, stream>>>(
        bufB, Bt3H, Bt3L, nullptr, bufA, nullptr, a_src3, a_dst3, ls, ld,
        NN, HID, HID, HID);
    agg_gather<1, true, true, false><<<NN, 64, 0, stream>>>(
        bufA, nullptr, ls, ld, rowptr, csr, b3, x0, bufB, NN);
    // ---- score head ----
    score_kernel<<<(NN + 7) / 8, 256, 0, stream>>>(bufB, Ws1, bs1, Ws2, bs2, out, NN);
}